// Round 1
// baseline (254.928 us; speedup 1.0000x reference)
//
#include <hip/hip_runtime.h>

#define HEADS 16
#define HD 64
#define SEQ 2048
#define DMODEL 1024
#define BATCH 2
#define MTOT (BATCH*SEQ)   // 4096

typedef unsigned short u16;
typedef __bf16 bf16;
typedef bf16 bf16x8 __attribute__((ext_vector_type(8)));
typedef float f32x4 __attribute__((ext_vector_type(4)));
typedef unsigned short u16x8 __attribute__((ext_vector_type(8)));

static __device__ __forceinline__ u16 f2bf(float f) {
  bf16 b = (bf16)f;
  return __builtin_bit_cast(u16, b);
}

// async global->LDS, 16B per lane. LDS dest must be wave-uniform base; HW
// scatters lane i at base + 16*i. Global src is per-lane.
static __device__ __forceinline__ void async16(u16* lds_base, const u16* g) {
  __builtin_amdgcn_global_load_lds(
      (const __attribute__((address_space(1))) unsigned int*)g,
      (__attribute__((address_space(3))) unsigned int*)lds_base,
      16, 0, 0);
}

// ---------------- convert x: f32 -> bf16, 8 elems/thread ----------------
__global__ __launch_bounds__(256) void k_cvt(const float* __restrict__ in,
                                             u16* __restrict__ out, int n8) {
  int i = blockIdx.x * blockDim.x + threadIdx.x;
  if (i >= n8) return;
  const float4* p = (const float4*)(in + (size_t)i * 8);
  float4 a = p[0], b = p[1];
  u16x8 r;
  r[0] = f2bf(a.x); r[1] = f2bf(a.y); r[2] = f2bf(a.z); r[3] = f2bf(a.w);
  r[4] = f2bf(b.x); r[5] = f2bf(b.y); r[6] = f2bf(b.z); r[7] = f2bf(b.w);
  *(u16x8*)(out + (size_t)i * 8) = r;
}

// ------------- convert + transpose W: f32 [K,N] -> bf16 [N,K] -------------
__global__ __launch_bounds__(256) void k_cvtT(const float* __restrict__ W0, const float* __restrict__ W1,
                                              const float* __restrict__ W2, const float* __restrict__ W3,
                                              u16* __restrict__ T0, u16* __restrict__ T1,
                                              u16* __restrict__ T2, u16* __restrict__ T3) {
  const float* W = blockIdx.z == 0 ? W0 : blockIdx.z == 1 ? W1 : blockIdx.z == 2 ? W2 : W3;
  u16*         T = blockIdx.z == 0 ? T0 : blockIdx.z == 1 ? T1 : blockIdx.z == 2 ? T2 : T3;
  __shared__ u16 tile[64 * 68];
  int t = threadIdx.x;
  int kb = blockIdx.y * 64, nb = blockIdx.x * 64;
#pragma unroll
  for (int i = 0; i < 4; ++i) {
    int c = t * 4 + i;       // 0..1023 chunks of 4 f32
    int row = c >> 4;        // k-local
    int c4 = c & 15;         // n-chunk
    float4 v = *(const float4*)&W[(size_t)(kb + row) * DMODEL + nb + c4 * 4];
    tile[row * 68 + c4 * 4 + 0] = f2bf(v.x);
    tile[row * 68 + c4 * 4 + 1] = f2bf(v.y);
    tile[row * 68 + c4 * 4 + 2] = f2bf(v.z);
    tile[row * 68 + c4 * 4 + 3] = f2bf(v.w);
  }
  __syncthreads();
#pragma unroll
  for (int i = 0; i < 2; ++i) {
    int c = t * 2 + i;       // 0..511
    int n = c >> 3;          // n-local
    int k8 = c & 7;
    u16x8 v;
#pragma unroll
    for (int e = 0; e < 8; ++e) v[e] = tile[(k8 * 8 + e) * 68 + n];
    *(u16x8*)&T[(size_t)(nb + n) * DMODEL + kb + k8 * 8] = v;
  }
}

// -------- GEMM: C[M,N] = A[M,K] @ BT[N,K]^T + bias --------
// MODE 0: out bf16 in [B,H,N,hd] head-split layout (QKV). MODE 1: out f32 [M,N].
template <int MODE>
__global__ __launch_bounds__(256) void k_gemm(
    const u16* __restrict__ A,
    const u16* __restrict__ BT0, const u16* __restrict__ BT1, const u16* __restrict__ BT2,
    const float* __restrict__ b0, const float* __restrict__ b1, const float* __restrict__ b2,
    void* __restrict__ O0, void* __restrict__ O1, void* __restrict__ O2,
    int M, int N, int K) {
  const u16* BT = blockIdx.z == 0 ? BT0 : blockIdx.z == 1 ? BT1 : BT2;
  const float* bias = blockIdx.z == 0 ? b0 : blockIdx.z == 1 ? b1 : b2;
  void* Out = blockIdx.z == 0 ? O0 : blockIdx.z == 1 ? O1 : O2;

  __shared__ u16 Ads[128 * 32];  // 8KB
  __shared__ u16 Bds[128 * 32];  // 8KB
  int tid = threadIdx.x, wid = tid >> 6, lane = tid & 63;
  int r = lane & 15, g = lane >> 4;
  int wm = wid >> 1, wn = wid & 1;
  int m0 = blockIdx.y * 128, n0 = blockIdx.x * 128;

  f32x4 acc[4][4];
  f32x4 zero4 = {0.f, 0.f, 0.f, 0.f};
#pragma unroll
  for (int mt = 0; mt < 4; ++mt)
#pragma unroll
    for (int nt = 0; nt < 4; ++nt) acc[mt][nt] = zero4;

  int srow = lane >> 2;  // 0..15
  int scb = lane & 3;    // 16B chunk along k

  for (int k0 = 0; k0 < K; k0 += 32) {
#pragma unroll
    for (int tt = 0; tt < 2; ++tt) {
      int inst = wid * 2 + tt;
      int row = inst * 16 + srow;
      async16(&Ads[inst * 512], &A[(size_t)(m0 + row) * K + k0 + scb * 8]);
      async16(&Bds[inst * 512], &BT[(size_t)(n0 + row) * K + k0 + scb * 8]);
    }
    __syncthreads();
    bf16x8 af[4], bfv[4];
#pragma unroll
    for (int mt = 0; mt < 4; ++mt)
      af[mt] = *(const bf16x8*)&Ads[(wm * 64 + mt * 16 + r) * 32 + g * 8];
#pragma unroll
    for (int nt = 0; nt < 4; ++nt)
      bfv[nt] = *(const bf16x8*)&Bds[(wn * 64 + nt * 16 + r) * 32 + g * 8];
#pragma unroll
    for (int mt = 0; mt < 4; ++mt)
#pragma unroll
      for (int nt = 0; nt < 4; ++nt)
        acc[mt][nt] = __builtin_amdgcn_mfma_f32_16x16x32_bf16(af[mt], bfv[nt], acc[mt][nt], 0, 0, 0);
    __syncthreads();
  }

#pragma unroll
  for (int nt = 0; nt < 4; ++nt) {
    int col = n0 + wn * 64 + nt * 16 + r;
    float bv = bias[col];
#pragma unroll
    for (int mt = 0; mt < 4; ++mt) {
      int rowb = m0 + wm * 64 + mt * 16 + g * 4;
#pragma unroll
      for (int j = 0; j < 4; ++j) {
        float v = acc[mt][nt][j] + bv;
        int row = rowb + j;
        if (MODE == 0) {
          int b = row >> 11, n = row & (SEQ - 1);
          int h = col >> 6, d = col & (HD - 1);
          ((u16*)Out)[((size_t)(b * HEADS + h) * SEQ + n) * HD + d] = f2bf(v);
        } else {
          ((float*)Out)[(size_t)row * N + col] = v;
        }
      }
    }
  }
}

// -------- flash attention: 1 block per (bh, 64-row q tile), 4 waves --------
__global__ __launch_bounds__(256) void k_attn(const u16* __restrict__ Q, const u16* __restrict__ Kg,
                                              const u16* __restrict__ V, u16* __restrict__ Oa) {
  __shared__ u16 Kds[32 * 64];      // 4KB, chunk-swizzled (c8 ^= row&7)
  __shared__ u16 VT[64 * 40];       // V^T, padded rows (40 elems = 80B)
  __shared__ u16 Pds[4][16 * 40];   // per-wave P, padded

  int tid = threadIdx.x, wid = tid >> 6, lane = tid & 63;
  int r = lane & 15, g = lane >> 4;
  int bh = blockIdx.y, qt = blockIdx.x;
  const size_t base = (size_t)bh * SEQ * HD;
  int q0 = qt * 64 + wid * 16;

  bf16x8 qf[2];
#pragma unroll
  for (int dk = 0; dk < 2; ++dk)
    qf[dk] = *(const bf16x8*)&Q[base + (size_t)(q0 + r) * HD + dk * 32 + g * 8];

  f32x4 oacc[4];
  f32x4 zero4 = {0.f, 0.f, 0.f, 0.f};
#pragma unroll
  for (int dt = 0; dt < 4; ++dt) oacc[dt] = zero4;
  float mrow[4], lrow[4];
#pragma unroll
  for (int j = 0; j < 4; ++j) { mrow[j] = -3e38f; lrow[j] = 0.f; }
  const float cs = 0.125f * 1.44269504089f;  // hd^-0.5 * log2(e)

  for (int kc = 0; kc < SEQ / 32; ++kc) {
    int kof = kc * 32;
    // K stage: wave wid stages rows wid*8..wid*8+8, source pre-swizzled
    {
      int row = wid * 8 + (lane >> 3);
      int sch = (lane & 7) ^ (row & 7);
      async16(&Kds[wid * 512], &Kg[base + (size_t)(kof + row) * HD + sch * 8]);
    }
    // V transpose stage (reg-staged): thread t loads V[kof + t&31][ (t>>5)*8 .. +8 ]
    {
      int vr = tid & 31, vc8 = tid >> 5;
      u16x8 vv = *(const u16x8*)&V[base + (size_t)(kof + vr) * HD + vc8 * 8];
#pragma unroll
      for (int e = 0; e < 8; ++e) VT[(vc8 * 8 + e) * 40 + vr] = vv[e];
    }
    __syncthreads();

    // S = Q K^T for 16 q-rows x 32 k-cols
    f32x4 sacc[2];
    sacc[0] = zero4; sacc[1] = zero4;
#pragma unroll
    for (int ct = 0; ct < 2; ++ct) {
#pragma unroll
      for (int dk = 0; dk < 2; ++dk) {
        int krow = ct * 16 + r;
        bf16x8 kf = *(const bf16x8*)&Kds[krow * 64 + (((dk << 2) | g) ^ (krow & 7)) * 8];
        sacc[ct] = __builtin_amdgcn_mfma_f32_16x16x32_bf16(qf[dk], kf, sacc[ct], 0, 0, 0);
      }
    }

    // online softmax (all 64 lanes; reduce over 16-lane group)
    float p0[4], p1[4], alpha[4], cm[4], rs[4];
#pragma unroll
    for (int j = 0; j < 4; ++j) {
      p0[j] = sacc[0][j] * cs;
      p1[j] = sacc[1][j] * cs;
      cm[j] = fmaxf(p0[j], p1[j]);
    }
#pragma unroll
    for (int s = 1; s < 16; s <<= 1) {
#pragma unroll
      for (int j = 0; j < 4; ++j) cm[j] = fmaxf(cm[j], __shfl_xor(cm[j], s));
    }
#pragma unroll
    for (int j = 0; j < 4; ++j) {
      float mn = fmaxf(mrow[j], cm[j]);
      alpha[j] = exp2f(mrow[j] - mn);
      p0[j] = exp2f(p0[j] - mn);
      p1[j] = exp2f(p1[j] - mn);
      rs[j] = p0[j] + p1[j];
      mrow[j] = mn;
    }
#pragma unroll
    for (int s = 1; s < 16; s <<= 1) {
#pragma unroll
      for (int j = 0; j < 4; ++j) rs[j] += __shfl_xor(rs[j], s);
    }
#pragma unroll
    for (int j = 0; j < 4; ++j) {
      lrow[j] = lrow[j] * alpha[j] + rs[j];
      Pds[wid][(g * 4 + j) * 40 + r] = f2bf(p0[j]);
      Pds[wid][(g * 4 + j) * 40 + 16 + r] = f2bf(p1[j]);
    }
#pragma unroll
    for (int dt = 0; dt < 4; ++dt)
#pragma unroll
      for (int j = 0; j < 4; ++j) oacc[dt][j] *= alpha[j];

    // wave-local LDS fence: P writes must land before P frag reads
    asm volatile("s_waitcnt lgkmcnt(0)" ::: "memory");
    __builtin_amdgcn_sched_barrier(0);

    // PV
    bf16x8 pf = *(const bf16x8*)&Pds[wid][r * 40 + g * 8];
#pragma unroll
    for (int dt = 0; dt < 4; ++dt) {
      bf16x8 vf = *(const bf16x8*)&VT[(dt * 16 + r) * 40 + g * 8];
      oacc[dt] = __builtin_amdgcn_mfma_f32_16x16x32_bf16(pf, vf, oacc[dt], 0, 0, 0);
    }
    __syncthreads();
  }

  // normalize and write attention output in [B, N, D] bf16 layout
  int b = bh >> 4, h = bh & 15;
  float inv[4];
#pragma unroll
  for (int j = 0; j < 4; ++j) inv[j] = 1.0f / lrow[j];
#pragma unroll
  for (int dt = 0; dt < 4; ++dt)
#pragma unroll
    for (int j = 0; j < 4; ++j) {
      int q = q0 + g * 4 + j;
      Oa[((size_t)(b * SEQ + q)) * DMODEL + h * HD + dt * 16 + r] = f2bf(oacc[dt][j] * inv[j]);
    }
}

extern "C" void kernel_launch(void* const* d_in, const int* in_sizes, int n_in,
                              void* d_out, int out_size, void* d_ws, size_t ws_size,
                              hipStream_t stream) {
  const float* x  = (const float*)d_in[0];
  const float* Wq = (const float*)d_in[1];
  const float* bq = (const float*)d_in[2];
  const float* Wk = (const float*)d_in[3];
  const float* bk = (const float*)d_in[4];
  const float* Wv = (const float*)d_in[5];
  const float* bv = (const float*)d_in[6];
  const float* Wo = (const float*)d_in[7];
  const float* bo = (const float*)d_in[8];

  char* ws = (char*)d_ws;
  const size_t MB = 1024 * 1024;
  u16* xb   = (u16*)(ws);            // 8 MB   x as bf16 [4096,1024]
  u16* wqT  = (u16*)(ws + 8 * MB);   // 2 MB   Wq^T bf16 [1024,1024]
  u16* wkT  = (u16*)(ws + 10 * MB);
  u16* wvT  = (u16*)(ws + 12 * MB);
  u16* woT  = (u16*)(ws + 14 * MB);
  u16* qbuf = (u16*)(ws + 16 * MB);  // 8 MB   [B,H,N,hd]
  u16* kbuf = (u16*)(ws + 24 * MB);
  u16* vbuf = (u16*)(ws + 32 * MB);
  u16* abuf = (u16*)(ws + 40 * MB);  // 8 MB   attn out bf16 [4096,1024]

  k_cvt<<<2048, 256, 0, stream>>>(x, xb, (MTOT * DMODEL) / 8);
  k_cvtT<<<dim3(16, 16, 4), 256, 0, stream>>>(Wq, Wk, Wv, Wo, wqT, wkT, wvT, woT);
  k_gemm<0><<<dim3(DMODEL / 128, MTOT / 128, 3), 256, 0, stream>>>(
      xb, wqT, wkT, wvT, bq, bk, bv, qbuf, kbuf, vbuf, MTOT, DMODEL, DMODEL);
  k_attn<<<dim3(SEQ / 64, BATCH * HEADS), 256, 0, stream>>>(qbuf, kbuf, vbuf, abuf);
  k_gemm<1><<<dim3(DMODEL / 128, MTOT / 128, 1), 256, 0, stream>>>(
      abuf, woT, woT, woT, bo, bo, bo, d_out, d_out, d_out, MTOT, DMODEL, DMODEL);
}

// Round 2
// 153.434 us; speedup vs baseline: 1.6615x; 1.6615x over previous
//
#include <hip/hip_runtime.h>

#define HEADS 16
#define HD 64
#define SEQ 2048
#define DMODEL 1024
#define BATCH 2
#define MTOT (BATCH*SEQ)   // 4096
#define KVB 64
#define NKC (SEQ/KVB)      // 32
#define PSTR 72            // P row stride (elems); 144B = 16B-aligned, low-conflict

typedef unsigned short u16;
typedef __bf16 bf16;
typedef bf16 bf16x8 __attribute__((ext_vector_type(8)));
typedef float f32x4 __attribute__((ext_vector_type(4)));
typedef unsigned short u16x8 __attribute__((ext_vector_type(8)));
typedef unsigned short u16x4 __attribute__((ext_vector_type(4)));

static __device__ __forceinline__ u16 f2bf(float f) {
  bf16 b = (bf16)f;
  return __builtin_bit_cast(u16, b);
}

// async global->LDS, 16B per lane. LDS dest is wave-uniform base; HW scatters
// lane i at base + 16*i. Global src is per-lane (enables source pre-swizzle).
static __device__ __forceinline__ void async16(u16* lds_base, const u16* g) {
  __builtin_amdgcn_global_load_lds(
      (const __attribute__((address_space(1))) unsigned int*)g,
      (__attribute__((address_space(3))) unsigned int*)lds_base,
      16, 0, 0);
}

// ---------------- convert x: f32 -> bf16, 8 elems/thread ----------------
__global__ __launch_bounds__(256) void k_cvt(const float* __restrict__ in,
                                             u16* __restrict__ out, int n8) {
  int i = blockIdx.x * blockDim.x + threadIdx.x;
  if (i >= n8) return;
  const float4* p = (const float4*)(in + (size_t)i * 8);
  float4 a = p[0], b = p[1];
  u16x8 r;
  r[0] = f2bf(a.x); r[1] = f2bf(a.y); r[2] = f2bf(a.z); r[3] = f2bf(a.w);
  r[4] = f2bf(b.x); r[5] = f2bf(b.y); r[6] = f2bf(b.z); r[7] = f2bf(b.w);
  *(u16x8*)(out + (size_t)i * 8) = r;
}

// ------------- convert + transpose W: f32 [K,N] -> bf16 [N,K] -------------
__global__ __launch_bounds__(256) void k_cvtT(const float* __restrict__ W0, const float* __restrict__ W1,
                                              const float* __restrict__ W2, const float* __restrict__ W3,
                                              u16* __restrict__ T0, u16* __restrict__ T1,
                                              u16* __restrict__ T2, u16* __restrict__ T3) {
  const float* W = blockIdx.z == 0 ? W0 : blockIdx.z == 1 ? W1 : blockIdx.z == 2 ? W2 : W3;
  u16*         T = blockIdx.z == 0 ? T0 : blockIdx.z == 1 ? T1 : blockIdx.z == 2 ? T2 : T3;
  __shared__ u16 tile[64 * 68];
  int t = threadIdx.x;
  int kb = blockIdx.y * 64, nb = blockIdx.x * 64;
#pragma unroll
  for (int i = 0; i < 4; ++i) {
    int c = t * 4 + i;
    int row = c >> 4;
    int c4 = c & 15;
    float4 v = *(const float4*)&W[(size_t)(kb + row) * DMODEL + nb + c4 * 4];
    tile[row * 68 + c4 * 4 + 0] = f2bf(v.x);
    tile[row * 68 + c4 * 4 + 1] = f2bf(v.y);
    tile[row * 68 + c4 * 4 + 2] = f2bf(v.z);
    tile[row * 68 + c4 * 4 + 3] = f2bf(v.w);
  }
  __syncthreads();
#pragma unroll
  for (int i = 0; i < 2; ++i) {
    int c = t * 2 + i;
    int n = c >> 3;
    int k8 = c & 7;
    u16x8 v;
#pragma unroll
    for (int e = 0; e < 8; ++e) v[e] = tile[(k8 * 8 + e) * 68 + n];
    *(u16x8*)&T[(size_t)(nb + n) * DMODEL + kb + k8 * 8] = v;
  }
}

// -------- GEMM: C[M,N] = A[M,K] @ BT[N,K]^T + bias --------
// MODE 0 (QKV): z=0 -> Q*(scale*log2e) head-split [bh][n][hd]
//               z=1 -> K head-split [bh][n][hd]
//               z=2 -> V^T [bh][hd][n]
// MODE 1: out f32 [M,N].
template <int MODE>
__global__ __launch_bounds__(256) void k_gemm(
    const u16* __restrict__ A,
    const u16* __restrict__ BT0, const u16* __restrict__ BT1, const u16* __restrict__ BT2,
    const float* __restrict__ b0, const float* __restrict__ b1, const float* __restrict__ b2,
    void* __restrict__ O0, void* __restrict__ O1, void* __restrict__ O2,
    int M, int N, int K) {
  const u16* BT = blockIdx.z == 0 ? BT0 : blockIdx.z == 1 ? BT1 : BT2;
  const float* bias = blockIdx.z == 0 ? b0 : blockIdx.z == 1 ? b1 : b2;
  void* Out = blockIdx.z == 0 ? O0 : blockIdx.z == 1 ? O1 : O2;

  __shared__ u16 Ads[128 * 32];
  __shared__ u16 Bds[128 * 32];
  int tid = threadIdx.x, wid = tid >> 6, lane = tid & 63;
  int r = lane & 15, g = lane >> 4;
  int wm = wid >> 1, wn = wid & 1;
  int m0 = blockIdx.y * 128, n0 = blockIdx.x * 128;

  f32x4 acc[4][4];
  f32x4 zero4 = {0.f, 0.f, 0.f, 0.f};
#pragma unroll
  for (int mt = 0; mt < 4; ++mt)
#pragma unroll
    for (int nt = 0; nt < 4; ++nt) acc[mt][nt] = zero4;

  int srow = lane >> 2;
  int scb = lane & 3;

  for (int k0 = 0; k0 < K; k0 += 32) {
#pragma unroll
    for (int tt = 0; tt < 2; ++tt) {
      int inst = wid * 2 + tt;
      int row = inst * 16 + srow;
      async16(&Ads[inst * 512], &A[(size_t)(m0 + row) * K + k0 + scb * 8]);
      async16(&Bds[inst * 512], &BT[(size_t)(n0 + row) * K + k0 + scb * 8]);
    }
    __syncthreads();
    bf16x8 af[4], bfv[4];
#pragma unroll
    for (int mt = 0; mt < 4; ++mt)
      af[mt] = *(const bf16x8*)&Ads[(wm * 64 + mt * 16 + r) * 32 + g * 8];
#pragma unroll
    for (int nt = 0; nt < 4; ++nt)
      bfv[nt] = *(const bf16x8*)&Bds[(wn * 64 + nt * 16 + r) * 32 + g * 8];
#pragma unroll
    for (int mt = 0; mt < 4; ++mt)
#pragma unroll
      for (int nt = 0; nt < 4; ++nt)
        acc[mt][nt] = __builtin_amdgcn_mfma_f32_16x16x32_bf16(af[mt], bfv[nt], acc[mt][nt], 0, 0, 0);
    __syncthreads();
  }

  const float qs = 0.18033688011112042f;  // hd^-0.5 * log2(e)
#pragma unroll
  for (int nt = 0; nt < 4; ++nt) {
    int col = n0 + wn * 64 + nt * 16 + r;
    float bv = bias[col];
#pragma unroll
    for (int mt = 0; mt < 4; ++mt) {
      int rowb = m0 + wm * 64 + mt * 16 + g * 4;
      if (MODE == 0) {
        int b = rowb >> 11;
        int h = col >> 6, d = col & (HD - 1);
        if (blockIdx.z == 2) {
          // V^T: [bh][d][n], 4 consecutive n -> one 8B store
          u16x4 pk;
#pragma unroll
          for (int j = 0; j < 4; ++j) pk[j] = f2bf(acc[mt][nt][j] + bv);
          *(u16x4*)&((u16*)Out)[((size_t)((b * HEADS + h) * HD + d)) * SEQ + (rowb & (SEQ - 1))] = pk;
        } else {
          float sc = (blockIdx.z == 0) ? qs : 1.0f;
#pragma unroll
          for (int j = 0; j < 4; ++j) {
            int row = rowb + j;
            int n = row & (SEQ - 1);
            ((u16*)Out)[((size_t)(b * HEADS + h) * SEQ + n) * HD + d] = f2bf((acc[mt][nt][j] + bv) * sc);
          }
        }
      } else {
#pragma unroll
        for (int j = 0; j < 4; ++j)
          ((float*)Out)[(size_t)(rowb + j) * N + col] = acc[mt][nt][j] + bv;
      }
    }
  }
}

// -------- flash attention: block = (bh, 128-q-rows), 4 waves x 32 q-rows --------
// KVB=64, double-buffered K and V^T staging via global_load_lds, T3-minimal
// 2-phase pipeline (raw s_barrier + manual vmcnt), ones-MFMA row sums,
// defer-max (THR=8, log2 domain; Q pre-scaled by scale*log2e).
__global__ __launch_bounds__(256, 2) void k_attn(const u16* __restrict__ Q,
                                                 const u16* __restrict__ Kg,
                                                 const u16* __restrict__ Vt,
                                                 u16* __restrict__ Oa) {
  __shared__ u16 Kds[2][KVB * 64];   // [k][d], 16B-chunk XOR swizzle by (row&7)
  __shared__ u16 Vds[2][KVB * 64];   // [d][k], same swizzle
  __shared__ u16 Pds[4][32 * PSTR];  // per-wave P[q_local][k]

  int tid = threadIdx.x, wid = tid >> 6, lane = tid & 63;
  int r = lane & 15, g = lane >> 4;

  // XCD-aware swizzle: 512 blocks, 8 XCDs -> 4 heads per XCD (K/V L2-resident)
  int fid = blockIdx.y * gridDim.x + blockIdx.x;  // gridDim = (16, 32)
  int swz = (fid & 7) * 64 + (fid >> 3);
  int qt = swz & 15;
  int bh = swz >> 4;

  const size_t kbase = (size_t)bh * SEQ * HD;  // Q,K: [bh][n][64]
  const size_t vbase = (size_t)bh * HD * SEQ;  // Vt:  [bh][64][2048]
  int q0 = qt * 128 + wid * 32;

  // Q fragments (pre-scaled in GEMM epilogue), hoisted
  bf16x8 qf[2][2];
#pragma unroll
  for (int s = 0; s < 2; ++s)
#pragma unroll
    for (int dk = 0; dk < 2; ++dk)
      qf[s][dk] = *(const bf16x8*)&Q[kbase + (size_t)(q0 + s * 16 + r) * HD + dk * 32 + g * 8];

  f32x4 zero4 = {0.f, 0.f, 0.f, 0.f};
  f32x4 oacc[2][4];
  f32x4 lacc[2];
  float mrow[2][4];
#pragma unroll
  for (int s = 0; s < 2; ++s) {
    lacc[s] = zero4;
#pragma unroll
    for (int dt = 0; dt < 4; ++dt) oacc[s][dt] = zero4;
#pragma unroll
    for (int j = 0; j < 4; ++j) mrow[s][j] = -3e38f;
  }

  u16x8 onesb;
#pragma unroll
  for (int e = 0; e < 8; ++e) onesb[e] = 0x3F80;  // bf16 1.0
  bf16x8 ones = __builtin_bit_cast(bf16x8, onesb);

  auto STAGE = [&](int b, int kc) {
    int kof = kc * KVB;
#pragma unroll
    for (int i = 0; i < 2; ++i) {
      int inst = wid * 2 + i;
      int rr = inst * 8 + (lane >> 3);
      int ch = (lane & 7) ^ (rr & 7);
      async16(&Kds[b][inst * 512], &Kg[kbase + (size_t)(kof + rr) * HD + ch * 8]);
      async16(&Vds[b][inst * 512], &Vt[vbase + (size_t)rr * SEQ + kof + ch * 8]);
    }
  };

  STAGE(0, 0);
  asm volatile("s_waitcnt vmcnt(0)" ::: "memory");
  __builtin_amdgcn_sched_barrier(0);
  __builtin_amdgcn_s_barrier();
  __builtin_amdgcn_sched_barrier(0);

  int buf = 0;
  for (int kc = 0; kc < NKC; ++kc) {
    if (kc + 1 < NKC) STAGE(buf ^ 1, kc + 1);  // flies under this iter's compute

    const u16* Kb = Kds[buf];
    const u16* Vb = Vds[buf];

    // ---- QK^T: both q-subtiles share each K fragment ----
    f32x4 sA[4], sB[4];
#pragma unroll
    for (int ct = 0; ct < 4; ++ct) { sA[ct] = zero4; sB[ct] = zero4; }
#pragma unroll
    for (int ct = 0; ct < 4; ++ct)
#pragma unroll
      for (int dk = 0; dk < 2; ++dk) {
        bf16x8 kf = *(const bf16x8*)&Kb[(ct * 16 + r) * 64 + (((dk * 4 + g) ^ (r & 7)) * 8)];
        sA[ct] = __builtin_amdgcn_mfma_f32_16x16x32_bf16(qf[0][dk], kf, sA[ct], 0, 0, 0);
        sB[ct] = __builtin_amdgcn_mfma_f32_16x16x32_bf16(qf[1][dk], kf, sB[ct], 0, 0, 0);
      }

    // ---- online softmax (exp2 domain), defer-max THR=8 ----
#pragma unroll
    for (int s = 0; s < 2; ++s) {
      f32x4* sx = (s == 0) ? sA : sB;
      float cm[4];
#pragma unroll
      for (int j = 0; j < 4; ++j)
        cm[j] = fmaxf(fmaxf(sx[0][j], sx[1][j]), fmaxf(sx[2][j], sx[3][j]));
      bool need = (cm[0] > mrow[s][0] + 8.f) | (cm[1] > mrow[s][1] + 8.f) |
                  (cm[2] > mrow[s][2] + 8.f) | (cm[3] > mrow[s][3] + 8.f);
      if (__any(need)) {
#pragma unroll
        for (int st = 1; st < 16; st <<= 1)
#pragma unroll
          for (int j = 0; j < 4; ++j) cm[j] = fmaxf(cm[j], __shfl_xor(cm[j], st));
#pragma unroll
        for (int j = 0; j < 4; ++j) {
          float mn = fmaxf(mrow[s][j], cm[j]);
          float al = exp2f(mrow[s][j] - mn);
          mrow[s][j] = mn;
          lacc[s][j] *= al;
#pragma unroll
          for (int dt = 0; dt < 4; ++dt) oacc[s][dt][j] *= al;
        }
      }
#pragma unroll
      for (int ct = 0; ct < 4; ++ct)
#pragma unroll
        for (int j = 0; j < 4; ++j) {
          float pe = exp2f(sx[ct][j] - mrow[s][j]);
          Pds[wid][(s * 16 + g * 4 + j) * PSTR + ct * 16 + r] = f2bf(pe);
        }
    }

    // wave-local fence: P writes land before P fragment reads (rule 18)
    asm volatile("s_waitcnt lgkmcnt(0)" ::: "memory");
    __builtin_amdgcn_sched_barrier(0);

    // ---- PV + row-sum via ones-MFMA; V fragments shared by both subtiles ----
#pragma unroll
    for (int kc2 = 0; kc2 < 2; ++kc2) {
      bf16x8 pfA = *(const bf16x8*)&Pds[wid][(r) * PSTR + kc2 * 32 + g * 8];
      bf16x8 pfB = *(const bf16x8*)&Pds[wid][(16 + r) * PSTR + kc2 * 32 + g * 8];
      lacc[0] = __builtin_amdgcn_mfma_f32_16x16x32_bf16(pfA, ones, lacc[0], 0, 0, 0);
      lacc[1] = __builtin_amdgcn_mfma_f32_16x16x32_bf16(pfB, ones, lacc[1], 0, 0, 0);
#pragma unroll
      for (int dt = 0; dt < 4; ++dt) {
        bf16x8 vf = *(const bf16x8*)&Vb[(dt * 16 + r) * 64 + (((kc2 * 4 + g) ^ (r & 7)) * 8)];
        oacc[0][dt] = __builtin_amdgcn_mfma_f32_16x16x32_bf16(pfA, vf, oacc[0][dt], 0, 0, 0);
        oacc[1][dt] = __builtin_amdgcn_mfma_f32_16x16x32_bf16(pfB, vf, oacc[1][dt], 0, 0, 0);
      }
    }

    // wait own next-tile stage, then block-wide barrier (no vmcnt drain at a
    // __syncthreads — this is the whole point)
    asm volatile("s_waitcnt vmcnt(0)" ::: "memory");
    __builtin_amdgcn_sched_barrier(0);
    __builtin_amdgcn_s_barrier();
    __builtin_amdgcn_sched_barrier(0);
    buf ^= 1;
  }

  // ---- normalize + write [B, N, D] bf16 ----
  int b = bh >> 4, h = bh & 15;
#pragma unroll
  for (int s = 0; s < 2; ++s) {
    float inv[4];
#pragma unroll
    for (int j = 0; j < 4; ++j) inv[j] = 1.0f / lacc[s][j];
#pragma unroll
    for (int dt = 0; dt < 4; ++dt)
#pragma unroll
      for (int j = 0; j < 4; ++j) {
        int q = q0 + s * 16 + g * 4 + j;
        Oa[((size_t)(b * SEQ + q)) * DMODEL + h * HD + dt * 16 + r] = f2bf(oacc[s][dt][j] * inv[j]);
      }
  }
}

extern "C" void kernel_launch(void* const* d_in, const int* in_sizes, int n_in,
                              void* d_out, int out_size, void* d_ws, size_t ws_size,
                              hipStream_t stream) {
  const float* x  = (const float*)d_in[0];
  const float* Wq = (const float*)d_in[1];
  const float* bq = (const float*)d_in[2];
  const float* Wk = (const float*)d_in[3];
  const float* bk = (const float*)d_in[4];
  const float* Wv = (const float*)d_in[5];
  const float* bv = (const float*)d_in[6];
  const float* Wo = (const float*)d_in[7];
  const float* bo = (const float*)d_in[8];

  char* ws = (char*)d_ws;
  const size_t MB = 1024 * 1024;
  u16* xb    = (u16*)(ws);            // 8 MB  x bf16 [4096,1024]
  u16* wqT   = (u16*)(ws + 8 * MB);   // 2 MB each, W^T bf16
  u16* wkT   = (u16*)(ws + 10 * MB);
  u16* wvT   = (u16*)(ws + 12 * MB);
  u16* woT   = (u16*)(ws + 14 * MB);
  u16* qbuf  = (u16*)(ws + 16 * MB);  // 8 MB [bh][n][hd] (pre-scaled)
  u16* kbuf  = (u16*)(ws + 24 * MB);  // 8 MB [bh][n][hd]
  u16* vbufT = (u16*)(ws + 32 * MB);  // 8 MB [bh][hd][n]
  u16* abuf  = (u16*)(ws + 40 * MB);  // 8 MB attn out bf16 [4096,1024]

  k_cvt<<<2048, 256, 0, stream>>>(x, xb, (MTOT * DMODEL) / 8);
  k_cvtT<<<dim3(16, 16, 4), 256, 0, stream>>>(Wq, Wk, Wv, Wo, wqT, wkT, wvT, woT);
  k_gemm<0><<<dim3(DMODEL / 128, MTOT / 128, 3), 256, 0, stream>>>(
      xb, wqT, wkT, wvT, bq, bk, bv, qbuf, kbuf, vbufT, MTOT, DMODEL, DMODEL);
  k_attn<<<dim3(SEQ / 128, BATCH * HEADS), 256, 0, stream>>>(qbuf, kbuf, vbufT, abuf);
  k_gemm<1><<<dim3(DMODEL / 128, MTOT / 128, 1), 256, 0, stream>>>(
      abuf, woT, woT, woT, bo, bo, bo, d_out, d_out, d_out, MTOT, DMODEL, DMODEL);
}

// Round 3
// 153.415 us; speedup vs baseline: 1.6617x; 1.0001x over previous
//
#include <hip/hip_runtime.h>

#define HEADS 16
#define HD 64
#define SEQ 2048
#define DMODEL 1024
#define BATCH 2
#define MTOT (BATCH*SEQ)   // 4096
#define KVB 64
#define NKC (SEQ/KVB)      // 32
#define PSTR 72            // P row stride (elems); 144B = 16B-aligned, low-conflict

typedef unsigned short u16;
typedef __bf16 bf16;
typedef bf16 bf16x8 __attribute__((ext_vector_type(8)));
typedef float f32x4 __attribute__((ext_vector_type(4)));
typedef unsigned short u16x8 __attribute__((ext_vector_type(8)));
typedef unsigned short u16x4 __attribute__((ext_vector_type(4)));

static __device__ __forceinline__ u16 f2bf(float f) {
  bf16 b = (bf16)f;
  return __builtin_bit_cast(u16, b);
}

// async global->LDS, 16B per lane. LDS dest is wave-uniform base; HW scatters
// lane i at base + 16*i. Global src is per-lane (enables source pre-swizzle).
static __device__ __forceinline__ void async16(u16* lds_base, const u16* g) {
  __builtin_amdgcn_global_load_lds(
      (const __attribute__((address_space(1))) unsigned int*)g,
      (__attribute__((address_space(3))) unsigned int*)lds_base,
      16, 0, 0);
}

// ---------------- convert x: f32 -> bf16, 8 elems/thread ----------------
__global__ __launch_bounds__(256) void k_cvt(const float* __restrict__ in,
                                             u16* __restrict__ out, int n8) {
  int i = blockIdx.x * blockDim.x + threadIdx.x;
  if (i >= n8) return;
  const float4* p = (const float4*)(in + (size_t)i * 8);
  float4 a = p[0], b = p[1];
  u16x8 r;
  r[0] = f2bf(a.x); r[1] = f2bf(a.y); r[2] = f2bf(a.z); r[3] = f2bf(a.w);
  r[4] = f2bf(b.x); r[5] = f2bf(b.y); r[6] = f2bf(b.z); r[7] = f2bf(b.w);
  *(u16x8*)(out + (size_t)i * 8) = r;
}

// ------------- convert + transpose W: f32 [K,N] -> bf16 [N,K] -------------
__global__ __launch_bounds__(256) void k_cvtT(const float* __restrict__ W0, const float* __restrict__ W1,
                                              const float* __restrict__ W2, const float* __restrict__ W3,
                                              u16* __restrict__ T0, u16* __restrict__ T1,
                                              u16* __restrict__ T2, u16* __restrict__ T3) {
  const float* W = blockIdx.z == 0 ? W0 : blockIdx.z == 1 ? W1 : blockIdx.z == 2 ? W2 : W3;
  u16*         T = blockIdx.z == 0 ? T0 : blockIdx.z == 1 ? T1 : blockIdx.z == 2 ? T2 : T3;
  __shared__ u16 tile[64 * 68];
  int t = threadIdx.x;
  int kb = blockIdx.y * 64, nb = blockIdx.x * 64;
#pragma unroll
  for (int i = 0; i < 4; ++i) {
    int c = t * 4 + i;
    int row = c >> 4;
    int c4 = c & 15;
    float4 v = *(const float4*)&W[(size_t)(kb + row) * DMODEL + nb + c4 * 4];
    tile[row * 68 + c4 * 4 + 0] = f2bf(v.x);
    tile[row * 68 + c4 * 4 + 1] = f2bf(v.y);
    tile[row * 68 + c4 * 4 + 2] = f2bf(v.z);
    tile[row * 68 + c4 * 4 + 3] = f2bf(v.w);
  }
  __syncthreads();
#pragma unroll
  for (int i = 0; i < 2; ++i) {
    int c = t * 2 + i;
    int n = c >> 3;
    int k8 = c & 7;
    u16x8 v;
#pragma unroll
    for (int e = 0; e < 8; ++e) v[e] = tile[(k8 * 8 + e) * 68 + n];
    *(u16x8*)&T[(size_t)(nb + n) * DMODEL + kb + k8 * 8] = v;
  }
}

// -------- GEMM: C[M,N] = A[M,K] @ BT[N,K]^T + bias --------
// MODE 0 (QKV): z=0 -> Q*(scale*log2e) head-split [bh][n][hd]
//               z=1 -> K head-split [bh][n][hd]
//               z=2 -> V^T [bh][hd][n]
// MODE 1: out f32 [M,N].
template <int MODE>
__global__ __launch_bounds__(256) void k_gemm(
    const u16* __restrict__ A,
    const u16* __restrict__ BT0, const u16* __restrict__ BT1, const u16* __restrict__ BT2,
    const float* __restrict__ b0, const float* __restrict__ b1, const float* __restrict__ b2,
    void* __restrict__ O0, void* __restrict__ O1, void* __restrict__ O2,
    int M, int N, int K) {
  const u16* BT = blockIdx.z == 0 ? BT0 : blockIdx.z == 1 ? BT1 : BT2;
  const float* bias = blockIdx.z == 0 ? b0 : blockIdx.z == 1 ? b1 : b2;
  void* Out = blockIdx.z == 0 ? O0 : blockIdx.z == 1 ? O1 : O2;

  __shared__ u16 Ads[128 * 32];
  __shared__ u16 Bds[128 * 32];
  int tid = threadIdx.x, wid = tid >> 6, lane = tid & 63;
  int r = lane & 15, g = lane >> 4;
  int wm = wid >> 1, wn = wid & 1;
  int m0 = blockIdx.y * 128, n0 = blockIdx.x * 128;

  f32x4 acc[4][4];
  f32x4 zero4 = {0.f, 0.f, 0.f, 0.f};
#pragma unroll
  for (int mt = 0; mt < 4; ++mt)
#pragma unroll
    for (int nt = 0; nt < 4; ++nt) acc[mt][nt] = zero4;

  int srow = lane >> 2;
  int scb = lane & 3;

  for (int k0 = 0; k0 < K; k0 += 32) {
#pragma unroll
    for (int tt = 0; tt < 2; ++tt) {
      int inst = wid * 2 + tt;
      int row = inst * 16 + srow;
      async16(&Ads[inst * 512], &A[(size_t)(m0 + row) * K + k0 + scb * 8]);
      async16(&Bds[inst * 512], &BT[(size_t)(n0 + row) * K + k0 + scb * 8]);
    }
    __syncthreads();
    bf16x8 af[4], bfv[4];
#pragma unroll
    for (int mt = 0; mt < 4; ++mt)
      af[mt] = *(const bf16x8*)&Ads[(wm * 64 + mt * 16 + r) * 32 + g * 8];
#pragma unroll
    for (int nt = 0; nt < 4; ++nt)
      bfv[nt] = *(const bf16x8*)&Bds[(wn * 64 + nt * 16 + r) * 32 + g * 8];
#pragma unroll
    for (int mt = 0; mt < 4; ++mt)
#pragma unroll
      for (int nt = 0; nt < 4; ++nt)
        acc[mt][nt] = __builtin_amdgcn_mfma_f32_16x16x32_bf16(af[mt], bfv[nt], acc[mt][nt], 0, 0, 0);
    __syncthreads();
  }

  const float qs = 0.18033688011112042f;  // hd^-0.5 * log2(e)
#pragma unroll
  for (int nt = 0; nt < 4; ++nt) {
    int col = n0 + wn * 64 + nt * 16 + r;
    float bv = bias[col];
#pragma unroll
    for (int mt = 0; mt < 4; ++mt) {
      int rowb = m0 + wm * 64 + mt * 16 + g * 4;
      if (MODE == 0) {
        int b = rowb >> 11;
        int h = col >> 6, d = col & (HD - 1);
        if (blockIdx.z == 2) {
          // V^T: [bh][d][n], 4 consecutive n -> one 8B store
          u16x4 pk;
#pragma unroll
          for (int j = 0; j < 4; ++j) pk[j] = f2bf(acc[mt][nt][j] + bv);
          *(u16x4*)&((u16*)Out)[((size_t)((b * HEADS + h) * HD + d)) * SEQ + (rowb & (SEQ - 1))] = pk;
        } else {
          float sc = (blockIdx.z == 0) ? qs : 1.0f;
#pragma unroll
          for (int j = 0; j < 4; ++j) {
            int row = rowb + j;
            int n = row & (SEQ - 1);
            ((u16*)Out)[((size_t)(b * HEADS + h) * SEQ + n) * HD + d] = f2bf((acc[mt][nt][j] + bv) * sc);
          }
        }
      } else {
#pragma unroll
        for (int j = 0; j < 4; ++j)
          ((float*)Out)[(size_t)(rowb + j) * N + col] = acc[mt][nt][j] + bv;
      }
    }
  }
}

// -------- flash attention: block = (bh, 128-q-rows), 4 waves x 32 q-rows --------
// KVB=64, double-buffered K and V^T staging via global_load_lds, T3-minimal
// 2-phase pipeline (raw s_barrier + manual vmcnt), ones-MFMA row sums,
// defer-max (THR=8, log2 domain; Q pre-scaled by scale*log2e).
__global__ __launch_bounds__(256, 2) void k_attn(const u16* __restrict__ Q,
                                                 const u16* __restrict__ Kg,
                                                 const u16* __restrict__ Vt,
                                                 u16* __restrict__ Oa) {
  __shared__ u16 Kds[2][KVB * 64];   // [k][d], 16B-chunk XOR swizzle by (row&7)
  __shared__ u16 Vds[2][KVB * 64];   // [d][k], same swizzle
  __shared__ u16 Pds[4][32 * PSTR];  // per-wave P[q_local][k]

  int tid = threadIdx.x, wid = tid >> 6, lane = tid & 63;
  int r = lane & 15, g = lane >> 4;

  // XCD-aware swizzle: 512 blocks, 8 XCDs -> 4 heads per XCD (K/V L2-resident)
  int fid = blockIdx.y * gridDim.x + blockIdx.x;  // gridDim = (16, 32)
  int swz = (fid & 7) * 64 + (fid >> 3);
  int qt = swz & 15;
  int bh = swz >> 4;

  const size_t kbase = (size_t)bh * SEQ * HD;  // Q,K: [bh][n][64]
  const size_t vbase = (size_t)bh * HD * SEQ;  // Vt:  [bh][64][2048]
  int q0 = qt * 128 + wid * 32;

  // Q fragments (pre-scaled in GEMM epilogue), hoisted
  bf16x8 qf[2][2];
#pragma unroll
  for (int s = 0; s < 2; ++s)
#pragma unroll
    for (int dk = 0; dk < 2; ++dk)
      qf[s][dk] = *(const bf16x8*)&Q[kbase + (size_t)(q0 + s * 16 + r) * HD + dk * 32 + g * 8];

  f32x4 zero4 = {0.f, 0.f, 0.f, 0.f};
  f32x4 oacc[2][4];
  f32x4 lacc[2];
  float mrow[2][4];
#pragma unroll
  for (int s = 0; s < 2; ++s) {
    lacc[s] = zero4;
#pragma unroll
    for (int dt = 0; dt < 4; ++dt) oacc[s][dt] = zero4;
#pragma unroll
    for (int j = 0; j < 4; ++j) mrow[s][j] = -3e38f;
  }

  u16x8 onesb;
#pragma unroll
  for (int e = 0; e < 8; ++e) onesb[e] = 0x3F80;  // bf16 1.0
  bf16x8 ones = __builtin_bit_cast(bf16x8, onesb);

  auto STAGE = [&](int b, int kc) {
    int kof = kc * KVB;
#pragma unroll
    for (int i = 0; i < 2; ++i) {
      int inst = wid * 2 + i;
      int rr = inst * 8 + (lane >> 3);
      int ch = (lane & 7) ^ (rr & 7);
      async16(&Kds[b][inst * 512], &Kg[kbase + (size_t)(kof + rr) * HD + ch * 8]);
      async16(&Vds[b][inst * 512], &Vt[vbase + (size_t)rr * SEQ + kof + ch * 8]);
    }
  };

  STAGE(0, 0);
  asm volatile("s_waitcnt vmcnt(0)" ::: "memory");
  __builtin_amdgcn_sched_barrier(0);
  __builtin_amdgcn_s_barrier();
  __builtin_amdgcn_sched_barrier(0);

  int buf = 0;
  for (int kc = 0; kc < NKC; ++kc) {
    if (kc + 1 < NKC) STAGE(buf ^ 1, kc + 1);  // flies under this iter's compute

    const u16* Kb = Kds[buf];
    const u16* Vb = Vds[buf];

    // ---- QK^T: both q-subtiles share each K fragment ----
    f32x4 sA[4], sB[4];
#pragma unroll
    for (int ct = 0; ct < 4; ++ct) { sA[ct] = zero4; sB[ct] = zero4; }
#pragma unroll
    for (int ct = 0; ct < 4; ++ct)
#pragma unroll
      for (int dk = 0; dk < 2; ++dk) {
        bf16x8 kf = *(const bf16x8*)&Kb[(ct * 16 + r) * 64 + (((dk * 4 + g) ^ (r & 7)) * 8)];
        sA[ct] = __builtin_amdgcn_mfma_f32_16x16x32_bf16(qf[0][dk], kf, sA[ct], 0, 0, 0);
        sB[ct] = __builtin_amdgcn_mfma_f32_16x16x32_bf16(qf[1][dk], kf, sB[ct], 0, 0, 0);
      }

    // ---- online softmax (exp2 domain), defer-max THR=8 ----
#pragma unroll
    for (int s = 0; s < 2; ++s) {
      f32x4* sx = (s == 0) ? sA : sB;
      float cm[4];
#pragma unroll
      for (int j = 0; j < 4; ++j)
        cm[j] = fmaxf(fmaxf(sx[0][j], sx[1][j]), fmaxf(sx[2][j], sx[3][j]));
      bool need = (cm[0] > mrow[s][0] + 8.f) | (cm[1] > mrow[s][1] + 8.f) |
                  (cm[2] > mrow[s][2] + 8.f) | (cm[3] > mrow[s][3] + 8.f);
      if (__any(need)) {
#pragma unroll
        for (int st = 1; st < 16; st <<= 1)
#pragma unroll
          for (int j = 0; j < 4; ++j) cm[j] = fmaxf(cm[j], __shfl_xor(cm[j], st));
#pragma unroll
        for (int j = 0; j < 4; ++j) {
          float mn = fmaxf(mrow[s][j], cm[j]);
          float al = exp2f(mrow[s][j] - mn);
          mrow[s][j] = mn;
          lacc[s][j] *= al;
#pragma unroll
          for (int dt = 0; dt < 4; ++dt) oacc[s][dt][j] *= al;
        }
      }
#pragma unroll
      for (int ct = 0; ct < 4; ++ct)
#pragma unroll
        for (int j = 0; j < 4; ++j) {
          float pe = exp2f(sx[ct][j] - mrow[s][j]);
          Pds[wid][(s * 16 + g * 4 + j) * PSTR + ct * 16 + r] = f2bf(pe);
        }
    }

    // wave-local fence: P writes land before P fragment reads (rule 18)
    asm volatile("s_waitcnt lgkmcnt(0)" ::: "memory");
    __builtin_amdgcn_sched_barrier(0);

    // ---- PV + row-sum via ones-MFMA; V fragments shared by both subtiles ----
#pragma unroll
    for (int kc2 = 0; kc2 < 2; ++kc2) {
      bf16x8 pfA = *(const bf16x8*)&Pds[wid][(r) * PSTR + kc2 * 32 + g * 8];
      bf16x8 pfB = *(const bf16x8*)&Pds[wid][(16 + r) * PSTR + kc2 * 32 + g * 8];
      lacc[0] = __builtin_amdgcn_mfma_f32_16x16x32_bf16(pfA, ones, lacc[0], 0, 0, 0);
      lacc[1] = __builtin_amdgcn_mfma_f32_16x16x32_bf16(pfB, ones, lacc[1], 0, 0, 0);
#pragma unroll
      for (int dt = 0; dt < 4; ++dt) {
        bf16x8 vf = *(const bf16x8*)&Vb[(dt * 16 + r) * 64 + (((kc2 * 4 + g) ^ (r & 7)) * 8)];
        oacc[0][dt] = __builtin_amdgcn_mfma_f32_16x16x32_bf16(pfA, vf, oacc[0][dt], 0, 0, 0);
        oacc[1][dt] = __builtin_amdgcn_mfma_f32_16x16x32_bf16(pfB, vf, oacc[1][dt], 0, 0, 0);
      }
    }

    // wait own next-tile stage, then block-wide barrier (no vmcnt drain at a
    // __syncthreads — this is the whole point)
    asm volatile("s_waitcnt vmcnt(0)" ::: "memory");
    __builtin_amdgcn_sched_barrier(0);
    __builtin_amdgcn_s_barrier();
    __builtin_amdgcn_sched_barrier(0);
    buf ^= 1;
  }

  // ---- normalize + write [B, N, D] bf16 ----
  int b = bh >> 4, h = bh & 15;
#pragma unroll
  for (int s = 0; s < 2; ++s) {
    float inv[4];
#pragma unroll
    for (int j = 0; j < 4; ++j) inv[j] = 1.0f / lacc[s][j];
#pragma unroll
    for (int dt = 0; dt < 4; ++dt)
#pragma unroll
      for (int j = 0; j < 4; ++j) {
        int q = q0 + s * 16 + g * 4 + j;
        Oa[((size_t)(b * SEQ + q)) * DMODEL + h * HD + dt * 16 + r] = f2bf(oacc[s][dt][j] * inv[j]);
      }
  }
}

extern "C" void kernel_launch(void* const* d_in, const int* in_sizes, int n_in,
                              void* d_out, int out_size, void* d_ws, size_t ws_size,
                              hipStream_t stream) {
  const float* x  = (const float*)d_in[0];
  const float* Wq = (const float*)d_in[1];
  const float* bq = (const float*)d_in[2];
  const float* Wk = (const float*)d_in[3];
  const float* bk = (const float*)d_in[4];
  const float* Wv = (const float*)d_in[5];
  const float* bv = (const float*)d_in[6];
  const float* Wo = (const float*)d_in[7];
  const float* bo = (const float*)d_in[8];

  char* ws = (char*)d_ws;
  const size_t MB = 1024 * 1024;
  u16* xb    = (u16*)(ws);            // 8 MB  x bf16 [4096,1024]
  u16* wqT   = (u16*)(ws + 8 * MB);   // 2 MB each, W^T bf16
  u16* wkT   = (u16*)(ws + 10 * MB);
  u16* wvT   = (u16*)(ws + 12 * MB);
  u16* woT   = (u16*)(ws + 14 * MB);
  u16* qbuf  = (u16*)(ws + 16 * MB);  // 8 MB [bh][n][hd] (pre-scaled)
  u16* kbuf  = (u16*)(ws + 24 * MB);  // 8 MB [bh][n][hd]
  u16* vbufT = (u16*)(ws + 32 * MB);  // 8 MB [bh][hd][n]
  u16* abuf  = (u16*)(ws + 40 * MB);  // 8 MB attn out bf16 [4096,1024]

  k_cvt<<<2048, 256, 0, stream>>>(x, xb, (MTOT * DMODEL) / 8);
  k_cvtT<<<dim3(16, 16, 4), 256, 0, stream>>>(Wq, Wk, Wv, Wo, wqT, wkT, wvT, woT);
  k_gemm<0><<<dim3(DMODEL / 128, MTOT / 128, 3), 256, 0, stream>>>(
      xb, wqT, wkT, wvT, bq, bk, bv, qbuf, kbuf, vbufT, MTOT, DMODEL, DMODEL);
  k_attn<<<dim3(SEQ / 128, BATCH * HEADS), 256, 0, stream>>>(qbuf, kbuf, vbufT, abuf);
  k_gemm<1><<<dim3(DMODEL / 128, MTOT / 128, 1), 256, 0, stream>>>(
      abuf, woT, woT, woT, bo, bo, bo, d_out, d_out, d_out, MTOT, DMODEL, DMODEL);
}